// Round 7
// baseline (1346.301 us; speedup 1.0000x reference)
//
#include <hip/hip_runtime.h>
#include <math.h>

#define NP 512
#define TT 12

typedef float f32x4 __attribute__((ext_vector_type(4)));
typedef __bf16 bf16x8 __attribute__((ext_vector_type(8)));

// ws float offsets
#define OFF_CURABS 0        // [2][N*2] double buffer (LLC-routed via agent atomics)
#define OFF_A      2048     // [2][N*64] double buffer (LLC-routed via agent atomics)
#define OFF_WIHT   67584    // 128*256 transposed W_ih (normal loads, stays hot in L2)
#define OFF_WHHT   100352   // 64*256 transposed W_hh
#define OFF_BAR    116736   // 16 ints: per-step barrier counters
// total 116752 floats = 467 KB

#define AT_LOAD(p)     __hip_atomic_load((p), __ATOMIC_RELAXED, __HIP_MEMORY_SCOPE_AGENT)
#define AT_STORE(p, v) __hip_atomic_store((p), (v), __ATOMIC_RELAXED, __HIP_MEMORY_SCOPE_AGENT)

__global__ __launch_bounds__(256) void init_k(
    const float* __restrict__ obs, const float* __restrict__ W_ih,
    const float* __restrict__ W_hh, float* __restrict__ ws) {
  int tid = blockIdx.x * 256 + threadIdx.x;   // 128 blocks -> 32768 threads
  if (tid < 1024) ws[OFF_CURABS + tid] = obs[7 * 1024 + tid];  // obs_traj_pos[-1]
  if (tid < 32768) {
    int k = tid >> 8, g = tid & 255;
    ws[OFF_WIHT + tid] = W_ih[g * 128 + k];
  }
  if (tid < 16384) {
    int k = tid >> 8, g = tid & 255;
    ws[OFF_WHHT + tid] = W_hh[g * 64 + k];
  }
  if (tid < 16) ((int*)(ws + OFF_BAR))[tid] = 0;  // re-zeroed every launch (ws is poisoned)
}

// Persistent: one block per pedestrian, all 12 steps, 1 sw barrier/step.
// NO cache-flushing fences anywhere. Cross-block data (A, curabs) moves via
// relaxed agent-scope atomics (sc1 -> coherent at LLC, bypassing L1/L2), so
// weights stay hot in L2 for the whole kernel. Barrier ordering: every wave's
// __syncthreads() drains vmcnt(0) before s_barrier, so all A-stores of a
// block are globally visible before its t0 increments the step counter.
__global__ __launch_bounds__(256, 2) void fused_k(
    const float* __restrict__ lastpos, const float* __restrict__ cc,
    const float* __restrict__ zz, const int* __restrict__ nei,
    const float* __restrict__ h0, const float* __restrict__ c0,
    const float* __restrict__ epsin,
    const float* __restrict__ W_in, const float* __restrict__ b_in,
    const float* __restrict__ b_ih, const float* __restrict__ b_hh,
    const float* __restrict__ Wl2p, const float* __restrict__ bl2p,
    const float* __restrict__ W_sp, const float* __restrict__ b_sp,
    const float* __restrict__ W1, const float* __restrict__ b1,
    const float* __restrict__ W2, const float* __restrict__ b2,
    float* __restrict__ out, float* __restrict__ ws) {
  __shared__ __align__(16) __bf16 h1buf[4][32 * 72];  // per-wave tiles
  __shared__ __align__(16) __bf16 W2T[64 * 72];
  __shared__ float absx[512], absy[512];
  __shared__ int   ml[512];
  __shared__ float wcl[128], bib[64], basev[64];
  __shared__ float red[4][64];
  __shared__ float hloc[64], csloc[64], ctxloc[64], prevp[2];
  __shared__ float emb[162], xpart[2][128], xvec[128], gl[256];

  int t = threadIdx.x;
  int b = blockIdx.x;
  int lane = t & 63, w = t >> 6;
  int quad = lane >> 4, col = lane & 15;
  int* bar = (int*)(ws + OFF_BAR);

  // ---- one-time init: block-local state + folded constants ----
  if (t < 64) {
    hloc[t] = h0[b * 64 + t];
    csloc[t] = c0[b * 64 + t];
    ctxloc[t] = 0.f;
    float s = b1[t];
    for (int e = 0; e < 32; ++e) s = fmaf(b_sp[e], W1[e * 64 + t], s);
    basev[t] = s;
  }
  if (t < 2) prevp[t] = lastpos[b * 2 + t];
  if (t < 128) {
    int d = t >> 6, m = t & 63;
    float s = 0.f;
    for (int e = 0; e < 32; ++e) s = fmaf(W_sp[d * 32 + e], W1[e * 64 + m], s);
    wcl[t] = s;
  }
  for (int e = t; e < 4096; e += 256)
    W2T[(e & 63) * 72 + (e >> 6)] = (__bf16)W2[e];
  __syncthreads();

  // W2 MFMA B-fragments, held in registers for the whole kernel
  bf16x8 bf00 = *(const bf16x8*)&W2T[(0 * 16 + col) * 72 + 0 * 32 + quad * 8];
  bf16x8 bf01 = *(const bf16x8*)&W2T[(0 * 16 + col) * 72 + 1 * 32 + quad * 8];
  bf16x8 bf10 = *(const bf16x8*)&W2T[(1 * 16 + col) * 72 + 0 * 32 + quad * 8];
  bf16x8 bf11 = *(const bf16x8*)&W2T[(1 * 16 + col) * 72 + 1 * 32 + quad * 8];
  bf16x8 bf20 = *(const bf16x8*)&W2T[(2 * 16 + col) * 72 + 0 * 32 + quad * 8];
  bf16x8 bf21 = *(const bf16x8*)&W2T[(2 * 16 + col) * 72 + 1 * 32 + quad * 8];
  bf16x8 bf30 = *(const bf16x8*)&W2T[(3 * 16 + col) * 72 + 0 * 32 + quad * 8];
  bf16x8 bf31 = *(const bf16x8*)&W2T[(3 * 16 + col) * 72 + 1 * 32 + quad * 8];
  float b2v0 = b2[col], b2v1 = b2[16 + col], b2v2 = b2[32 + col], b2v3 = b2[48 + col];

  const float* wiht = ws + OFF_WIHT;
  const float* whht = ws + OFF_WHHT;

  for (int st = 0; st < TT; ++st) {
    float* Aab = ws + OFF_A + (st & 1) * 32768;

    // ================= row phase (all state block-local) =================
    if (t < 162) {
      float v;
      if (t < 2)       v = prevp[t];
      else if (t < 66) v = cc[b * 64 + (t - 2)];
      else if (t < 98) v = zz[b * 32 + (t - 66)];
      else             v = ctxloc[t - 98];
      emb[t] = v;
    }
    __syncthreads();
    {   // x = relu(emb @ W_in + b_in), split-K 2 ways
      int k = t & 127, p = t >> 7;
      float a0 = 0.f, a1 = 0.f;
      int d = p;
      for (; d + 2 < 162; d += 4) {
        a0 = fmaf(emb[d],     W_in[d * 128 + k],       a0);
        a1 = fmaf(emb[d + 2], W_in[(d + 2) * 128 + k], a1);
      }
      if (d < 162) a0 = fmaf(emb[d], W_in[d * 128 + k], a0);
      xpart[p][k] = a0 + a1;
    }
    __syncthreads();
    if (t < 128) xvec[t] = fmaxf(xpart[0][t] + xpart[1][t] + b_in[t], 0.f);
    __syncthreads();
    {   // gates
      int g = t;
      float s0 = 0.f, s1 = 0.f, s2 = 0.f, s3 = 0.f;
      for (int kk = 0; kk < 128; kk += 4) {
        s0 = fmaf(xvec[kk],     wiht[kk * 256 + g],       s0);
        s1 = fmaf(xvec[kk + 1], wiht[(kk + 1) * 256 + g], s1);
        s2 = fmaf(xvec[kk + 2], wiht[(kk + 2) * 256 + g], s2);
        s3 = fmaf(xvec[kk + 3], wiht[(kk + 3) * 256 + g], s3);
      }
      for (int kk = 0; kk < 64; kk += 4) {
        s0 = fmaf(hloc[kk],     whht[kk * 256 + g],       s0);
        s1 = fmaf(hloc[kk + 1], whht[(kk + 1) * 256 + g], s1);
        s2 = fmaf(hloc[kk + 2], whht[(kk + 2) * 256 + g], s2);
        s3 = fmaf(hloc[kk + 3], whht[(kk + 3) * 256 + g], s3);
      }
      gl[g] = b_ih[g] + b_hh[g] + ((s0 + s1) + (s2 + s3));
    }
    __syncthreads();
    if (t < 64) {   // LSTM update, in-place in LDS
      float ig = gl[t], fg = gl[64 + t], gg = gl[128 + t], og = gl[192 + t];
      float is = 1.f / (1.f + expf(-ig));
      float fs = 1.f / (1.f + expf(-fg));
      float os = 1.f / (1.f + expf(-og));
      float cn = fs * csloc[t] + is * tanhf(gg);
      csloc[t] = cn;
      hloc[t] = os * tanhf(cn);
    }
    __syncthreads();
    if (t < 128) {  // A -> LLC (agent atomic, parity dbuf); B -> bib (LDS only)
      int which = t >> 6, m = t & 63;
      const float* wb = W1 + (32 + which * 64) * 64 + m;
      float s0 = 0.f, s1 = 0.f, s2 = 0.f, s3 = 0.f;
      for (int k = 0; k < 64; k += 4) {
        s0 = fmaf(hloc[k],     wb[k * 64],       s0);
        s1 = fmaf(hloc[k + 1], wb[(k + 1) * 64], s1);
        s2 = fmaf(hloc[k + 2], wb[(k + 2) * 64], s2);
        s3 = fmaf(hloc[k + 3], wb[(k + 3) * 64], s3);
      }
      float sv = (s0 + s1) + (s2 + s3);
      if (which == 0) AT_STORE(&Aab[b * 64 + m], sv + basev[m]);
      else            bib[m] = sv;
    }

    // ========= grid barrier: relaxed agent atomics, NO cache flush =========
    __syncthreads();   // vmcnt(0) drain in every wave -> A-stores visible at LLC
    if (t == 0) {
      __hip_atomic_fetch_add(&bar[st], 1, __ATOMIC_RELAXED, __HIP_MEMORY_SCOPE_AGENT);
      while (__hip_atomic_load(&bar[st], __ATOMIC_RELAXED, __HIP_MEMORY_SCOPE_AGENT) < NP)
        __builtin_amdgcn_s_sleep(4);
    }
    __syncthreads();

    // ================= pool phase =================
    const float* curabs  = ws + OFF_CURABS + (st & 1) * 1024;
    float*       curabsw = ws + OFF_CURABS + ((st & 1) ^ 1) * 1024;
    const int* neirow = nei + ((size_t)st * NP + b) * NP;
    for (int e = t; e < 1024; e += 256) {        // curabs via LLC (atomic loads)
      float v = AT_LOAD(&curabs[e]);
      if (e & 1) absy[e >> 1] = v; else absx[e >> 1] = v;
    }
    for (int j = t; j < 512; j += 256) ml[j] = neirow[j];
    __syncthreads();

    float px = absx[b], py = absy[b];
    float wcx = wcl[lane], wcy = wcl[64 + lane];
    float bi  = bib[lane];
    float vmax0 = 0.f, vmax1 = 0.f, vmax2 = 0.f, vmax3 = 0.f;
    __bf16* myh1 = h1buf[w];

    for (int c = 0; c < 4; ++c) {
      int jbase = w * 128 + c * 32;
      // layer 1: 16-deep pipelined LLC loads of A, then compute+store bf16
      for (int half = 0; half < 2; ++half) {
        int j0 = jbase + half * 16;
        float av[16];
        #pragma unroll
        for (int jj = 0; jj < 16; ++jj)
          av[jj] = AT_LOAD(&Aab[(j0 + jj) * 64 + lane]);
        #pragma unroll
        for (int jj = 0; jj < 16; ++jj) {
          int jg = j0 + jj;
          float v = fmaf(px - absx[jg], wcx,
                    fmaf(py - absy[jg], wcy, av[jj] + bi));
          myh1[(half * 16 + jj) * 72 + lane] = (__bf16)fmaxf(v, 0.f);
        }
      }
      // layer 2: MFMA over the wave-private tile (no barrier needed)
      #pragma unroll
      for (int js = 0; js < 2; ++js) {
        bf16x8 a0 = *(const bf16x8*)&myh1[(js * 16 + col) * 72 + 0 * 32 + quad * 8];
        bf16x8 a1 = *(const bf16x8*)&myh1[(js * 16 + col) * 72 + 1 * 32 + quad * 8];
        int rowb = jbase + js * 16 + quad * 4;
        bool mk0 = ml[rowb] > 0, mk1 = ml[rowb + 1] > 0,
             mk2 = ml[rowb + 2] > 0, mk3 = ml[rowb + 3] > 0;
        f32x4 acc;
        acc = (f32x4){0.f, 0.f, 0.f, 0.f};
        acc = __builtin_amdgcn_mfma_f32_16x16x32_bf16(a0, bf00, acc, 0, 0, 0);
        acc = __builtin_amdgcn_mfma_f32_16x16x32_bf16(a1, bf01, acc, 0, 0, 0);
        vmax0 = fmaxf(vmax0, mk0 ? acc[0] + b2v0 : 0.f);
        vmax0 = fmaxf(vmax0, mk1 ? acc[1] + b2v0 : 0.f);
        vmax0 = fmaxf(vmax0, mk2 ? acc[2] + b2v0 : 0.f);
        vmax0 = fmaxf(vmax0, mk3 ? acc[3] + b2v0 : 0.f);
        acc = (f32x4){0.f, 0.f, 0.f, 0.f};
        acc = __builtin_amdgcn_mfma_f32_16x16x32_bf16(a0, bf10, acc, 0, 0, 0);
        acc = __builtin_amdgcn_mfma_f32_16x16x32_bf16(a1, bf11, acc, 0, 0, 0);
        vmax1 = fmaxf(vmax1, mk0 ? acc[0] + b2v1 : 0.f);
        vmax1 = fmaxf(vmax1, mk1 ? acc[1] + b2v1 : 0.f);
        vmax1 = fmaxf(vmax1, mk2 ? acc[2] + b2v1 : 0.f);
        vmax1 = fmaxf(vmax1, mk3 ? acc[3] + b2v1 : 0.f);
        acc = (f32x4){0.f, 0.f, 0.f, 0.f};
        acc = __builtin_amdgcn_mfma_f32_16x16x32_bf16(a0, bf20, acc, 0, 0, 0);
        acc = __builtin_amdgcn_mfma_f32_16x16x32_bf16(a1, bf21, acc, 0, 0, 0);
        vmax2 = fmaxf(vmax2, mk0 ? acc[0] + b2v2 : 0.f);
        vmax2 = fmaxf(vmax2, mk1 ? acc[1] + b2v2 : 0.f);
        vmax2 = fmaxf(vmax2, mk2 ? acc[2] + b2v2 : 0.f);
        vmax2 = fmaxf(vmax2, mk3 ? acc[3] + b2v2 : 0.f);
        acc = (f32x4){0.f, 0.f, 0.f, 0.f};
        acc = __builtin_amdgcn_mfma_f32_16x16x32_bf16(a0, bf30, acc, 0, 0, 0);
        acc = __builtin_amdgcn_mfma_f32_16x16x32_bf16(a1, bf31, acc, 0, 0, 0);
        vmax3 = fmaxf(vmax3, mk0 ? acc[0] + b2v3 : 0.f);
        vmax3 = fmaxf(vmax3, mk1 ? acc[1] + b2v3 : 0.f);
        vmax3 = fmaxf(vmax3, mk2 ? acc[2] + b2v3 : 0.f);
        vmax3 = fmaxf(vmax3, mk3 ? acc[3] + b2v3 : 0.f);
      }
    }
    vmax0 = fmaxf(vmax0, __shfl_xor(vmax0, 16));
    vmax0 = fmaxf(vmax0, __shfl_xor(vmax0, 32));
    vmax1 = fmaxf(vmax1, __shfl_xor(vmax1, 16));
    vmax1 = fmaxf(vmax1, __shfl_xor(vmax1, 32));
    vmax2 = fmaxf(vmax2, __shfl_xor(vmax2, 16));
    vmax2 = fmaxf(vmax2, __shfl_xor(vmax2, 32));
    vmax3 = fmaxf(vmax3, __shfl_xor(vmax3, 16));
    vmax3 = fmaxf(vmax3, __shfl_xor(vmax3, 32));
    if (lane < 16) {
      red[w][0 * 16 + lane] = vmax0;
      red[w][1 * 16 + lane] = vmax1;
      red[w][2 * 16 + lane] = vmax2;
      red[w][3 * 16 + lane] = vmax3;
    }
    __syncthreads();
    if (t < 64) {
      float m4 = fmaxf(fmaxf(red[0][t], red[1][t]),
                       fmaxf(red[2][t], red[3][t]));
      ctxloc[t] = m4;
    }
    __syncthreads();
    if (t < 64) {   // epilogue for pedestrian b
      int l = t;
      float cl = ctxloc[l];
      float sc0 = cl * Wl2p[(32 + l) * 2 + 0];
      float sc1 = cl * Wl2p[(32 + l) * 2 + 1];
      float m0 = 0.f, m1 = 0.f, v0 = 0.f, v1 = 0.f;
      if (l < 32) {
        float hm = hloc[l];
        m0 = hm * Wl2p[l * 2 + 0]; m1 = hm * Wl2p[l * 2 + 1];
        float hv = hloc[32 + l];
        v0 = hv * Wl2p[l * 2 + 0]; v1 = hv * Wl2p[l * 2 + 1];
      }
      for (int off = 32; off >= 1; off >>= 1) {
        sc0 += __shfl_down(sc0, off);
        sc1 += __shfl_down(sc1, off);
        m0  += __shfl_down(m0,  off);
        m1  += __shfl_down(m1,  off);
        v0  += __shfl_down(v0,  off);
        v1  += __shfl_down(v1,  off);
      }
      if (l == 0) {
        float mu0 = m0 + sc0 + bl2p[0], mu1 = m1 + sc1 + bl2p[1];
        float lv0 = v0 + sc0 + bl2p[0], lv1 = v1 + sc1 + bl2p[1];
        float e0 = epsin[st * 1024 + b * 2 + 0];
        float e1 = epsin[st * 1024 + b * 2 + 1];
        float p0 = mu0 + e0 * expf(0.5f * lv0);
        float p1 = mu1 + e1 * expf(0.5f * lv1);
        out[st * 1024 + b * 2 + 0] = p0;
        out[st * 1024 + b * 2 + 1] = p1;
        out[12288 + st * 1024 + b * 2 + 0] = mu0;
        out[12288 + st * 1024 + b * 2 + 1] = mu1;
        out[24576 + st * 1024 + b * 2 + 0] = lv0;
        out[24576 + st * 1024 + b * 2 + 1] = lv1;
        AT_STORE(&curabsw[b * 2 + 0], px + p0);
        AT_STORE(&curabsw[b * 2 + 1], py + p1);
        prevp[0] = p0;
        prevp[1] = p1;
      }
    }
    __syncthreads();   // prevp/ctxloc ready for next step's row phase
  }
}

extern "C" void kernel_launch(void* const* d_in, const int* in_sizes, int n_in,
                              void* d_out, int out_size, void* d_ws, size_t ws_size,
                              hipStream_t stream) {
  const float* lastpos = (const float*)d_in[0];
  const float* cc      = (const float*)d_in[1];
  const float* zz      = (const float*)d_in[2];
  const float* obs     = (const float*)d_in[3];
  const int*   nei     = (const int*)d_in[4];
  const float* h0      = (const float*)d_in[6];
  const float* c0      = (const float*)d_in[7];
  const float* eps     = (const float*)d_in[8];
  const float* W_in    = (const float*)d_in[9];
  const float* b_in    = (const float*)d_in[10];
  const float* W_ih    = (const float*)d_in[11];
  const float* W_hh    = (const float*)d_in[12];
  const float* b_ih    = (const float*)d_in[13];
  const float* b_hh    = (const float*)d_in[14];
  const float* W_l2p   = (const float*)d_in[15];
  const float* b_l2p   = (const float*)d_in[16];
  const float* W_sp    = (const float*)d_in[17];
  const float* b_sp    = (const float*)d_in[18];
  const float* W1      = (const float*)d_in[19];
  const float* b1      = (const float*)d_in[20];
  const float* W2      = (const float*)d_in[21];
  const float* b2      = (const float*)d_in[22];
  float* out = (float*)d_out;
  float* ws  = (float*)d_ws;

  hipLaunchKernelGGL(init_k, dim3(128), dim3(256), 0, stream,
                     obs, W_ih, W_hh, ws);
  hipLaunchKernelGGL(fused_k, dim3(NP), dim3(256), 0, stream,
                     lastpos, cc, zz, nei, h0, c0, eps,
                     W_in, b_in, b_ih, b_hh, W_l2p, b_l2p, W_sp, b_sp,
                     W1, b1, W2, b2, out, ws);
}

// Round 10
// 369.427 us; speedup vs baseline: 3.6443x; 3.6443x over previous
//
#include <hip/hip_runtime.h>
#include <math.h>

#define NP 512
#define TT 12

typedef float f32x4 __attribute__((ext_vector_type(4)));
typedef __bf16 bf16x8 __attribute__((ext_vector_type(8)));

// ws float offsets
#define OFF_CURABS 0        // [2][N*2] double buffer (per-block self read/write only)
#define OFF_Q      2048     // [2][N*64]  Q_j = A_j + base - px_j*wcx - py_j*wcy
#define OFF_P      67584    // [N*64]     P_i = B_i + px_i*wcx + py_i*wcy (self-read only)
#define OFF_WIHT   100352   // 128*256 transposed W_ih
#define OFF_WHHT   133120   // 64*256 transposed W_hh
#define OFF_WC     149504   // [2][64]  W_sp @ W1[0:32]
#define OFF_BASE   149632   // [64]     b1 + b_sp @ W1[0:32]
#define OFF_H      149696   // N*64
#define OFF_CS     182464   // N*64
// total 215232 floats = 861 KB

__global__ __launch_bounds__(256) void init_k(
    const float* __restrict__ obs, const float* __restrict__ W_ih,
    const float* __restrict__ W_hh, const float* __restrict__ W_sp,
    const float* __restrict__ b_sp, const float* __restrict__ W1,
    const float* __restrict__ b1, float* __restrict__ ws) {
  int tid = blockIdx.x * 256 + threadIdx.x;   // 128 blocks -> 32768 threads
  if (tid < 1024) ws[OFF_CURABS + tid] = obs[7 * 1024 + tid];  // obs_traj_pos[-1]
  if (tid < 32768) {
    int k = tid >> 8, g = tid & 255;
    ws[OFF_WIHT + tid] = W_ih[g * 128 + k];
  }
  if (tid < 16384) {
    int k = tid >> 8, g = tid & 255;
    ws[OFF_WHHT + tid] = W_hh[g * 64 + k];
  }
  if (tid < 128) {
    int d = tid >> 6, m = tid & 63;
    float s = 0.f;
    for (int e = 0; e < 32; ++e) s = fmaf(W_sp[d * 32 + e], W1[e * 64 + m], s);
    ws[OFF_WC + tid] = s;
  }
  if (tid < 64) {
    float s = b1[tid];
    for (int e = 0; e < 32; ++e) s = fmaf(b_sp[e], W1[e * 64 + tid], s);
    ws[OFF_BASE + tid] = s;
  }
}

// Dispatch s in [0,12]: pool(s-1) if s>0, then row(s) if s<12.
// One block per pedestrian. Kernel boundary = coherent grid barrier.
// Separable layer-1: v[i,j,m] = P_i[m] + Q_j[m]; pool builds MFMA A-fragments
// directly in registers from float4 Q loads (no h1 LDS, no position staging).
__global__ __launch_bounds__(256) void step_k(
    const float* __restrict__ lastpos, const float* __restrict__ cc,
    const float* __restrict__ zz, const int* __restrict__ nei,
    const float* __restrict__ h0, const float* __restrict__ c0,
    const float* __restrict__ obs, const float* __restrict__ epsin,
    const float* __restrict__ W_in, const float* __restrict__ b_in,
    const float* __restrict__ b_ih, const float* __restrict__ b_hh,
    const float* __restrict__ Wl2p, const float* __restrict__ bl2p,
    const float* __restrict__ W1, const float* __restrict__ W2,
    const float* __restrict__ b2,
    float* __restrict__ out, float* __restrict__ ws, int s) {
  __shared__ __align__(16) __bf16 W2T[64 * 72];
  __shared__ int   ml[512];
  __shared__ float wcl[128], basev[64];
  __shared__ float red[4][64];
  __shared__ float hloc[64], csloc[64], ctxloc[64], prevp[2], pxy[2];
  __shared__ float emb[162], xpart[2][128], xvec[128], gl[256];

  int t = threadIdx.x;
  int b = blockIdx.x;
  int lane = t & 63, w = t >> 6;
  int quad = lane >> 4, col = lane & 15;

  // ---- staging ----
  if (t < 64) {
    if (s == 0) { hloc[t] = h0[b * 64 + t]; csloc[t] = c0[b * 64 + t]; ctxloc[t] = 0.f; }
    else        { hloc[t] = ws[OFF_H + b * 64 + t]; csloc[t] = ws[OFF_CS + b * 64 + t]; }
    basev[t] = ws[OFF_BASE + t];
  } else if (t < 192) {
    wcl[t - 64] = ws[OFF_WC + (t - 64)];
  }
  if (s == 0 && t < 2) {
    prevp[t] = lastpos[b * 2 + t];
    pxy[t]   = obs[7 * 1024 + b * 2 + t];   // curabs(0)[b]
  }
  if (s > 0) {
    for (int e = t; e < 4096; e += 256)
      W2T[(e & 63) * 72 + (e >> 6)] = (__bf16)W2[e];
    const int* neirow = nei + ((size_t)(s - 1) * NP + b) * NP;
    for (int j = t; j < 512; j += 256) ml[j] = neirow[j];
  }
  __syncthreads();

  // ================= pool phase: st = s-1 =================
  if (s > 0) {
    int st = s - 1;
    const float* Qb = ws + OFF_Q + (st & 1) * 32768;
    bf16x8 bf00 = *(const bf16x8*)&W2T[(0 * 16 + col) * 72 + 0 * 32 + quad * 8];
    bf16x8 bf01 = *(const bf16x8*)&W2T[(0 * 16 + col) * 72 + 1 * 32 + quad * 8];
    bf16x8 bf10 = *(const bf16x8*)&W2T[(1 * 16 + col) * 72 + 0 * 32 + quad * 8];
    bf16x8 bf11 = *(const bf16x8*)&W2T[(1 * 16 + col) * 72 + 1 * 32 + quad * 8];
    bf16x8 bf20 = *(const bf16x8*)&W2T[(2 * 16 + col) * 72 + 0 * 32 + quad * 8];
    bf16x8 bf21 = *(const bf16x8*)&W2T[(2 * 16 + col) * 72 + 1 * 32 + quad * 8];
    bf16x8 bf30 = *(const bf16x8*)&W2T[(3 * 16 + col) * 72 + 0 * 32 + quad * 8];
    bf16x8 bf31 = *(const bf16x8*)&W2T[(3 * 16 + col) * 72 + 1 * 32 + quad * 8];
    // P slices this lane needs (quad-uniform scalar loads, L1-broadcast)
    float pl0[8], pl1[8];
    #pragma unroll
    for (int e = 0; e < 8; ++e) {
      pl0[e] = ws[OFF_P + b * 64 + quad * 8 + e];
      pl1[e] = ws[OFF_P + b * 64 + 32 + quad * 8 + e];
    }
    float vmax0 = -1e30f, vmax1 = -1e30f, vmax2 = -1e30f, vmax3 = -1e30f;

    for (int c = 0; c < 8; ++c) {
      int j0 = w * 128 + c * 16;
      int jr = (j0 + col) * 64 + quad * 8;
      f32x4 qa = *(const f32x4*)&Qb[jr];
      f32x4 qb = *(const f32x4*)&Qb[jr + 4];
      f32x4 qc = *(const f32x4*)&Qb[jr + 32];
      f32x4 qd = *(const f32x4*)&Qb[jr + 36];
      bf16x8 a0, a1;
      #pragma unroll
      for (int e = 0; e < 4; ++e) {
        a0[e]     = (__bf16)fmaxf(qa[e] + pl0[e],     0.f);
        a0[e + 4] = (__bf16)fmaxf(qb[e] + pl0[e + 4], 0.f);
        a1[e]     = (__bf16)fmaxf(qc[e] + pl1[e],     0.f);
        a1[e + 4] = (__bf16)fmaxf(qd[e] + pl1[e + 4], 0.f);
      }
      int mrow = j0 + quad * 4;
      bool mk0 = ml[mrow] > 0, mk1 = ml[mrow + 1] > 0,
           mk2 = ml[mrow + 2] > 0, mk3 = ml[mrow + 3] > 0;
      f32x4 acc;
      acc = (f32x4){0.f, 0.f, 0.f, 0.f};
      acc = __builtin_amdgcn_mfma_f32_16x16x32_bf16(a0, bf00, acc, 0, 0, 0);
      acc = __builtin_amdgcn_mfma_f32_16x16x32_bf16(a1, bf01, acc, 0, 0, 0);
      vmax0 = fmaxf(vmax0, mk0 ? acc[0] : -1e30f);
      vmax0 = fmaxf(vmax0, mk1 ? acc[1] : -1e30f);
      vmax0 = fmaxf(vmax0, mk2 ? acc[2] : -1e30f);
      vmax0 = fmaxf(vmax0, mk3 ? acc[3] : -1e30f);
      acc = (f32x4){0.f, 0.f, 0.f, 0.f};
      acc = __builtin_amdgcn_mfma_f32_16x16x32_bf16(a0, bf10, acc, 0, 0, 0);
      acc = __builtin_amdgcn_mfma_f32_16x16x32_bf16(a1, bf11, acc, 0, 0, 0);
      vmax1 = fmaxf(vmax1, mk0 ? acc[0] : -1e30f);
      vmax1 = fmaxf(vmax1, mk1 ? acc[1] : -1e30f);
      vmax1 = fmaxf(vmax1, mk2 ? acc[2] : -1e30f);
      vmax1 = fmaxf(vmax1, mk3 ? acc[3] : -1e30f);
      acc = (f32x4){0.f, 0.f, 0.f, 0.f};
      acc = __builtin_amdgcn_mfma_f32_16x16x32_bf16(a0, bf20, acc, 0, 0, 0);
      acc = __builtin_amdgcn_mfma_f32_16x16x32_bf16(a1, bf21, acc, 0, 0, 0);
      vmax2 = fmaxf(vmax2, mk0 ? acc[0] : -1e30f);
      vmax2 = fmaxf(vmax2, mk1 ? acc[1] : -1e30f);
      vmax2 = fmaxf(vmax2, mk2 ? acc[2] : -1e30f);
      vmax2 = fmaxf(vmax2, mk3 ? acc[3] : -1e30f);
      acc = (f32x4){0.f, 0.f, 0.f, 0.f};
      acc = __builtin_amdgcn_mfma_f32_16x16x32_bf16(a0, bf30, acc, 0, 0, 0);
      acc = __builtin_amdgcn_mfma_f32_16x16x32_bf16(a1, bf31, acc, 0, 0, 0);
      vmax3 = fmaxf(vmax3, mk0 ? acc[0] : -1e30f);
      vmax3 = fmaxf(vmax3, mk1 ? acc[1] : -1e30f);
      vmax3 = fmaxf(vmax3, mk2 ? acc[2] : -1e30f);
      vmax3 = fmaxf(vmax3, mk3 ? acc[3] : -1e30f);
    }
    vmax0 = fmaxf(vmax0, __shfl_xor(vmax0, 16));
    vmax0 = fmaxf(vmax0, __shfl_xor(vmax0, 32));
    vmax1 = fmaxf(vmax1, __shfl_xor(vmax1, 16));
    vmax1 = fmaxf(vmax1, __shfl_xor(vmax1, 32));
    vmax2 = fmaxf(vmax2, __shfl_xor(vmax2, 16));
    vmax2 = fmaxf(vmax2, __shfl_xor(vmax2, 32));
    vmax3 = fmaxf(vmax3, __shfl_xor(vmax3, 16));
    vmax3 = fmaxf(vmax3, __shfl_xor(vmax3, 32));
    if (lane < 16) {
      red[w][0 * 16 + lane] = vmax0;
      red[w][1 * 16 + lane] = vmax1;
      red[w][2 * 16 + lane] = vmax2;
      red[w][3 * 16 + lane] = vmax3;
    }
    __syncthreads();
    if (t < 64) {
      float m4 = fmaxf(fmaxf(red[0][t], red[1][t]),
                       fmaxf(red[2][t], red[3][t]));
      ctxloc[t] = fmaxf(m4 + b2[t], 0.f);   // b2-hoist + relu; empty -> 0
    }
    __syncthreads();
    if (t < 64) {   // epilogue: mu/logvar/pos for pedestrian b
      int l = t;
      float cl = ctxloc[l];
      float sc0 = cl * Wl2p[(32 + l) * 2 + 0];
      float sc1 = cl * Wl2p[(32 + l) * 2 + 1];
      float m0 = 0.f, m1 = 0.f, v0 = 0.f, v1 = 0.f;
      if (l < 32) {
        float hm = hloc[l];
        m0 = hm * Wl2p[l * 2 + 0]; m1 = hm * Wl2p[l * 2 + 1];
        float hv = hloc[32 + l];
        v0 = hv * Wl2p[l * 2 + 0]; v1 = hv * Wl2p[l * 2 + 1];
      }
      for (int off = 32; off >= 1; off >>= 1) {
        sc0 += __shfl_down(sc0, off);
        sc1 += __shfl_down(sc1, off);
        m0  += __shfl_down(m0,  off);
        m1  += __shfl_down(m1,  off);
        v0  += __shfl_down(v0,  off);
        v1  += __shfl_down(v1,  off);
      }
      if (l == 0) {
        float mu0 = m0 + sc0 + bl2p[0], mu1 = m1 + sc1 + bl2p[1];
        float lv0 = v0 + sc0 + bl2p[0], lv1 = v1 + sc1 + bl2p[1];
        float e0 = epsin[st * 1024 + b * 2 + 0];
        float e1 = epsin[st * 1024 + b * 2 + 1];
        float p0 = mu0 + e0 * expf(0.5f * lv0);
        float p1 = mu1 + e1 * expf(0.5f * lv1);
        out[st * 1024 + b * 2 + 0] = p0;
        out[st * 1024 + b * 2 + 1] = p1;
        out[12288 + st * 1024 + b * 2 + 0] = mu0;
        out[12288 + st * 1024 + b * 2 + 1] = mu1;
        out[24576 + st * 1024 + b * 2 + 0] = lv0;
        out[24576 + st * 1024 + b * 2 + 1] = lv1;
        float px = ws[OFF_CURABS + (st & 1) * 1024 + b * 2 + 0];
        float py = ws[OFF_CURABS + (st & 1) * 1024 + b * 2 + 1];
        float nx = px + p0, ny = py + p1;
        ws[OFF_CURABS + ((st & 1) ^ 1) * 1024 + b * 2 + 0] = nx;
        ws[OFF_CURABS + ((st & 1) ^ 1) * 1024 + b * 2 + 1] = ny;
        pxy[0] = nx; pxy[1] = ny;     // position for step s (used by Q/P write)
        prevp[0] = p0; prevp[1] = p1;
      }
    }
    __syncthreads();   // prevp/ctxloc/pxy ready for row phase
  }

  // ================= row phase: st = s =================
  if (s < TT) {
    if (t < 162) {
      float v;
      if (t < 2)       v = prevp[t];
      else if (t < 66) v = cc[b * 64 + (t - 2)];
      else if (t < 98) v = zz[b * 32 + (t - 66)];
      else             v = ctxloc[t - 98];
      emb[t] = v;
    }
    __syncthreads();
    {   // x = relu(emb @ W_in + b_in), split-K 2 ways
      int k = t & 127, p = t >> 7;
      float a0 = 0.f, a1 = 0.f;
      int d = p;
      for (; d + 2 < 162; d += 4) {
        a0 = fmaf(emb[d],     W_in[d * 128 + k],       a0);
        a1 = fmaf(emb[d + 2], W_in[(d + 2) * 128 + k], a1);
      }
      if (d < 162) a0 = fmaf(emb[d], W_in[d * 128 + k], a0);
      xpart[p][k] = a0 + a1;
    }
    __syncthreads();
    if (t < 128) xvec[t] = fmaxf(xpart[0][t] + xpart[1][t] + b_in[t], 0.f);
    __syncthreads();
    {   // gates
      int g = t;
      const float* wiht = ws + OFF_WIHT;
      const float* whht = ws + OFF_WHHT;
      float s0 = 0.f, s1 = 0.f, s2 = 0.f, s3 = 0.f;
      for (int kk = 0; kk < 128; kk += 4) {
        s0 = fmaf(xvec[kk],     wiht[kk * 256 + g],       s0);
        s1 = fmaf(xvec[kk + 1], wiht[(kk + 1) * 256 + g], s1);
        s2 = fmaf(xvec[kk + 2], wiht[(kk + 2) * 256 + g], s2);
        s3 = fmaf(xvec[kk + 3], wiht[(kk + 3) * 256 + g], s3);
      }
      for (int kk = 0; kk < 64; kk += 4) {
        s0 = fmaf(hloc[kk],     whht[kk * 256 + g],       s0);
        s1 = fmaf(hloc[kk + 1], whht[(kk + 1) * 256 + g], s1);
        s2 = fmaf(hloc[kk + 2], whht[(kk + 2) * 256 + g], s2);
        s3 = fmaf(hloc[kk + 3], whht[(kk + 3) * 256 + g], s3);
      }
      gl[g] = b_ih[g] + b_hh[g] + ((s0 + s1) + (s2 + s3));
    }
    __syncthreads();
    if (t < 64) {   // LSTM update; persist h,cs for next dispatch
      float ig = gl[t], fg = gl[64 + t], gg = gl[128 + t], og = gl[192 + t];
      float is = 1.f / (1.f + expf(-ig));
      float fs = 1.f / (1.f + expf(-fg));
      float os = 1.f / (1.f + expf(-og));
      float cn = fs * csloc[t] + is * tanhf(gg);
      float hv = os * tanhf(cn);
      hloc[t] = hv;
      ws[OFF_CS + b * 64 + t] = cn;
      ws[OFF_H + b * 64 + t] = hv;
    }
    __syncthreads();
    if (t < 128) {  // Q(s) -> ws dbuf[s&1]; P(s) -> ws (self-read only)
      int which = t >> 6, m = t & 63;
      const float* wb = W1 + (32 + which * 64) * 64 + m;
      float s0 = 0.f, s1 = 0.f, s2 = 0.f, s3 = 0.f;
      for (int k = 0; k < 64; k += 4) {
        s0 = fmaf(hloc[k],     wb[k * 64],       s0);
        s1 = fmaf(hloc[k + 1], wb[(k + 1) * 64], s1);
        s2 = fmaf(hloc[k + 2], wb[(k + 2) * 64], s2);
        s3 = fmaf(hloc[k + 3], wb[(k + 3) * 64], s3);
      }
      float sv = (s0 + s1) + (s2 + s3);
      float cx = pxy[0], cy = pxy[1];
      if (which == 0)
        ws[OFF_Q + (s & 1) * 32768 + b * 64 + m] =
            sv + basev[m] - cx * wcl[m] - cy * wcl[64 + m];
      else
        ws[OFF_P + b * 64 + m] = sv + cx * wcl[m] + cy * wcl[64 + m];
    }
  }
}

extern "C" void kernel_launch(void* const* d_in, const int* in_sizes, int n_in,
                              void* d_out, int out_size, void* d_ws, size_t ws_size,
                              hipStream_t stream) {
  const float* lastpos = (const float*)d_in[0];
  const float* cc      = (const float*)d_in[1];
  const float* zz      = (const float*)d_in[2];
  const float* obs     = (const float*)d_in[3];
  const int*   nei     = (const int*)d_in[4];
  const float* h0      = (const float*)d_in[6];
  const float* c0      = (const float*)d_in[7];
  const float* eps     = (const float*)d_in[8];
  const float* W_in    = (const float*)d_in[9];
  const float* b_in    = (const float*)d_in[10];
  const float* W_ih    = (const float*)d_in[11];
  const float* W_hh    = (const float*)d_in[12];
  const float* b_ih    = (const float*)d_in[13];
  const float* b_hh    = (const float*)d_in[14];
  const float* W_l2p   = (const float*)d_in[15];
  const float* b_l2p   = (const float*)d_in[16];
  const float* W_sp    = (const float*)d_in[17];
  const float* b_sp    = (const float*)d_in[18];
  const float* W1      = (const float*)d_in[19];
  const float* b1      = (const float*)d_in[20];
  const float* W2      = (const float*)d_in[21];
  const float* b2      = (const float*)d_in[22];
  float* out = (float*)d_out;
  float* ws  = (float*)d_ws;

  hipLaunchKernelGGL(init_k, dim3(128), dim3(256), 0, stream,
                     obs, W_ih, W_hh, W_sp, b_sp, W1, b1, ws);
  for (int s = 0; s <= TT; ++s) {
    hipLaunchKernelGGL(step_k, dim3(NP), dim3(256), 0, stream,
                       lastpos, cc, zz, nei, h0, c0, obs, eps,
                       W_in, b_in, b_ih, b_hh, W_l2p, b_l2p,
                       W1, W2, b2, out, ws, s);
  }
}

// Round 11
// 335.333 us; speedup vs baseline: 4.0148x; 1.1017x over previous
//
#include <hip/hip_runtime.h>
#include <math.h>

#define NP 512
#define TT 12

typedef float f32x4 __attribute__((ext_vector_type(4)));
typedef __bf16 bf16x8 __attribute__((ext_vector_type(8)));

// ws float offsets
#define OFF_CURABS 0        // [2][N*2]
#define OFF_Q      2048     // [2][N*64]  Q_j = A_j + base - px_j*wcx - py_j*wcy
#define OFF_P      67584    // [N*64]     P_i = B_i + px_i*wcx + py_i*wcy
#define OFF_H      100352   // N*64
#define OFF_CS     133120   // N*64
#define OFF_XCZ    165888   // [N*128]  [c|z] @ W_in[2:98]  (constant across steps)
#define OFF_WGB    231424   // bf16 [192][256]: rows 0..127 = W_ih^T, 128..191 = W_hh^T
#define OFF_WCTXB  256000   // bf16 [64][128]: W_in rows 98..161
#define OFF_W1B    260096   // bf16 [128][64]: W1 rows 32..159
#define OFF_WIN01  264192   // fp32 [2][128]: W_in rows 0,1
#define OFF_WC     264448   // [2][64]  W_sp @ W1[0:32]
#define OFF_BASE   264576   // [64]     b1 + b_sp @ W1[0:32]
// total 264640 floats ~= 1.06 MB

__global__ __launch_bounds__(256) void init_k(
    const float* __restrict__ obs, const float* __restrict__ cc,
    const float* __restrict__ zz,
    const float* __restrict__ W_in, const float* __restrict__ W_ih,
    const float* __restrict__ W_hh, const float* __restrict__ W_sp,
    const float* __restrict__ b_sp, const float* __restrict__ W1,
    const float* __restrict__ b1, float* __restrict__ ws) {
  if (blockIdx.x < 128) {
    int id = blockIdx.x * 256 + threadIdx.x;   // 0..32767
    if (id < 1024) ws[OFF_CURABS + id] = obs[7 * 1024 + id];  // obs_traj_pos[-1]
    __bf16* wgb = (__bf16*)(ws + OFF_WGB);
    for (int e = id; e < 49152; e += 32768) {
      int k = e >> 8, g = e & 255;
      float v = (k < 128) ? W_ih[g * 128 + k] : W_hh[g * 64 + (k - 128)];
      wgb[e] = (__bf16)v;
    }
    if (id < 8192) {
      int d = id >> 7, k = id & 127;
      ((__bf16*)(ws + OFF_WCTXB))[id] = (__bf16)W_in[(98 + d) * 128 + k];
    }
    if (id < 8192) {
      int r = id >> 6, m = id & 63;
      ((__bf16*)(ws + OFF_W1B))[id] = (__bf16)W1[(32 + r) * 64 + m];
    }
    if (id < 256) ws[OFF_WIN01 + id] = W_in[(id >> 7) * 128 + (id & 127)];
    if (id < 128) {
      int d = id >> 6, m = id & 63;
      float s = 0.f;
      for (int e = 0; e < 32; ++e) s = fmaf(W_sp[d * 32 + e], W1[e * 64 + m], s);
      ws[OFF_WC + id] = s;
    }
    if (id < 64) {
      float s = b1[id];
      for (int e = 0; e < 32; ++e) s = fmaf(b_sp[e], W1[e * 64 + id], s);
      ws[OFF_BASE + id] = s;
    }
  } else {
    // Xcz[b][k] = sum_{d<96} [c|z][b][d] * W_in[2+d][k]
    int b = blockIdx.x - 128;
    int k = threadIdx.x;
    if (k < 128) {
      float s = 0.f;
      for (int d = 0; d < 64; ++d) s = fmaf(cc[b * 64 + d], W_in[(2 + d) * 128 + k], s);
      for (int d = 0; d < 32; ++d) s = fmaf(zz[b * 32 + d], W_in[(66 + d) * 128 + k], s);
      ws[OFF_XCZ + b * 128 + k] = s;
    }
  }
}

// Dispatch s in [0,12]: pool(s-1) if s>0, then row(s) if s<12.
// One block per pedestrian. Kernel boundary = coherent grid barrier.
__global__ __launch_bounds__(256) void step_k(
    const float* __restrict__ lastpos, const int* __restrict__ nei,
    const float* __restrict__ h0, const float* __restrict__ c0,
    const float* __restrict__ obs, const float* __restrict__ epsin,
    const float* __restrict__ b_in,
    const float* __restrict__ b_ih, const float* __restrict__ b_hh,
    const float* __restrict__ Wl2p, const float* __restrict__ bl2p,
    const float* __restrict__ W2, const float* __restrict__ b2,
    float* __restrict__ out, float* __restrict__ ws, int s) {
  __shared__ __align__(16) __bf16 W2T[64 * 72];
  __shared__ int   ml[512];
  __shared__ float wcl[128], basev[64];
  __shared__ float red[4][64];
  __shared__ float hloc[64], csloc[64], ctxloc[64], prevp[2], pxy[2];
  __shared__ float xpart[2][128], xvec[128], gl[256];

  int t = threadIdx.x;
  int b = blockIdx.x;
  int lane = t & 63, w = t >> 6;
  int quad = lane >> 4, col = lane & 15;

  // ---- staging ----
  if (t < 64) {
    if (s == 0) { hloc[t] = h0[b * 64 + t]; csloc[t] = c0[b * 64 + t]; ctxloc[t] = 0.f; }
    else        { hloc[t] = ws[OFF_H + b * 64 + t]; csloc[t] = ws[OFF_CS + b * 64 + t]; }
    basev[t] = ws[OFF_BASE + t];
  } else if (t < 192) {
    wcl[t - 64] = ws[OFF_WC + (t - 64)];
  }
  if (s == 0 && t < 2) {
    prevp[t] = lastpos[b * 2 + t];
    pxy[t]   = obs[7 * 1024 + b * 2 + t];
  }
  if (s > 0) {
    for (int e = t; e < 4096; e += 256)
      W2T[(e & 63) * 72 + (e >> 6)] = (__bf16)W2[e];
    const int* neirow = nei + ((size_t)(s - 1) * NP + b) * NP;
    for (int j = t; j < 512; j += 256) ml[j] = neirow[j];
  }
  __syncthreads();

  // ================= pool phase: st = s-1 =================
  if (s > 0) {
    int st = s - 1;
    const float* Qb = ws + OFF_Q + (st & 1) * 32768;
    bf16x8 bf00 = *(const bf16x8*)&W2T[(0 * 16 + col) * 72 + 0 * 32 + quad * 8];
    bf16x8 bf01 = *(const bf16x8*)&W2T[(0 * 16 + col) * 72 + 1 * 32 + quad * 8];
    bf16x8 bf10 = *(const bf16x8*)&W2T[(1 * 16 + col) * 72 + 0 * 32 + quad * 8];
    bf16x8 bf11 = *(const bf16x8*)&W2T[(1 * 16 + col) * 72 + 1 * 32 + quad * 8];
    bf16x8 bf20 = *(const bf16x8*)&W2T[(2 * 16 + col) * 72 + 0 * 32 + quad * 8];
    bf16x8 bf21 = *(const bf16x8*)&W2T[(2 * 16 + col) * 72 + 1 * 32 + quad * 8];
    bf16x8 bf30 = *(const bf16x8*)&W2T[(3 * 16 + col) * 72 + 0 * 32 + quad * 8];
    bf16x8 bf31 = *(const bf16x8*)&W2T[(3 * 16 + col) * 72 + 1 * 32 + quad * 8];
    float pl0[8], pl1[8];
    #pragma unroll
    for (int e = 0; e < 8; ++e) {
      pl0[e] = ws[OFF_P + b * 64 + quad * 8 + e];
      pl1[e] = ws[OFF_P + b * 64 + 32 + quad * 8 + e];
    }
    float vmax0 = -1e30f, vmax1 = -1e30f, vmax2 = -1e30f, vmax3 = -1e30f;

    for (int c = 0; c < 8; ++c) {
      int j0 = w * 128 + c * 16;
      int jr = (j0 + col) * 64 + quad * 8;
      f32x4 qa = *(const f32x4*)&Qb[jr];
      f32x4 qb = *(const f32x4*)&Qb[jr + 4];
      f32x4 qc = *(const f32x4*)&Qb[jr + 32];
      f32x4 qd = *(const f32x4*)&Qb[jr + 36];
      bf16x8 a0, a1;
      #pragma unroll
      for (int e = 0; e < 4; ++e) {
        a0[e]     = (__bf16)fmaxf(qa[e] + pl0[e],     0.f);
        a0[e + 4] = (__bf16)fmaxf(qb[e] + pl0[e + 4], 0.f);
        a1[e]     = (__bf16)fmaxf(qc[e] + pl1[e],     0.f);
        a1[e + 4] = (__bf16)fmaxf(qd[e] + pl1[e + 4], 0.f);
      }
      int mrow = j0 + quad * 4;
      bool mk0 = ml[mrow] > 0, mk1 = ml[mrow + 1] > 0,
           mk2 = ml[mrow + 2] > 0, mk3 = ml[mrow + 3] > 0;
      f32x4 acc;
      acc = (f32x4){0.f, 0.f, 0.f, 0.f};
      acc = __builtin_amdgcn_mfma_f32_16x16x32_bf16(a0, bf00, acc, 0, 0, 0);
      acc = __builtin_amdgcn_mfma_f32_16x16x32_bf16(a1, bf01, acc, 0, 0, 0);
      vmax0 = fmaxf(vmax0, mk0 ? acc[0] : -1e30f);
      vmax0 = fmaxf(vmax0, mk1 ? acc[1] : -1e30f);
      vmax0 = fmaxf(vmax0, mk2 ? acc[2] : -1e30f);
      vmax0 = fmaxf(vmax0, mk3 ? acc[3] : -1e30f);
      acc = (f32x4){0.f, 0.f, 0.f, 0.f};
      acc = __builtin_amdgcn_mfma_f32_16x16x32_bf16(a0, bf10, acc, 0, 0, 0);
      acc = __builtin_amdgcn_mfma_f32_16x16x32_bf16(a1, bf11, acc, 0, 0, 0);
      vmax1 = fmaxf(vmax1, mk0 ? acc[0] : -1e30f);
      vmax1 = fmaxf(vmax1, mk1 ? acc[1] : -1e30f);
      vmax1 = fmaxf(vmax1, mk2 ? acc[2] : -1e30f);
      vmax1 = fmaxf(vmax1, mk3 ? acc[3] : -1e30f);
      acc = (f32x4){0.f, 0.f, 0.f, 0.f};
      acc = __builtin_amdgcn_mfma_f32_16x16x32_bf16(a0, bf20, acc, 0, 0, 0);
      acc = __builtin_amdgcn_mfma_f32_16x16x32_bf16(a1, bf21, acc, 0, 0, 0);
      vmax2 = fmaxf(vmax2, mk0 ? acc[0] : -1e30f);
      vmax2 = fmaxf(vmax2, mk1 ? acc[1] : -1e30f);
      vmax2 = fmaxf(vmax2, mk2 ? acc[2] : -1e30f);
      vmax2 = fmaxf(vmax2, mk3 ? acc[3] : -1e30f);
      acc = (f32x4){0.f, 0.f, 0.f, 0.f};
      acc = __builtin_amdgcn_mfma_f32_16x16x32_bf16(a0, bf30, acc, 0, 0, 0);
      acc = __builtin_amdgcn_mfma_f32_16x16x32_bf16(a1, bf31, acc, 0, 0, 0);
      vmax3 = fmaxf(vmax3, mk0 ? acc[0] : -1e30f);
      vmax3 = fmaxf(vmax3, mk1 ? acc[1] : -1e30f);
      vmax3 = fmaxf(vmax3, mk2 ? acc[2] : -1e30f);
      vmax3 = fmaxf(vmax3, mk3 ? acc[3] : -1e30f);
    }
    vmax0 = fmaxf(vmax0, __shfl_xor(vmax0, 16));
    vmax0 = fmaxf(vmax0, __shfl_xor(vmax0, 32));
    vmax1 = fmaxf(vmax1, __shfl_xor(vmax1, 16));
    vmax1 = fmaxf(vmax1, __shfl_xor(vmax1, 32));
    vmax2 = fmaxf(vmax2, __shfl_xor(vmax2, 16));
    vmax2 = fmaxf(vmax2, __shfl_xor(vmax2, 32));
    vmax3 = fmaxf(vmax3, __shfl_xor(vmax3, 16));
    vmax3 = fmaxf(vmax3, __shfl_xor(vmax3, 32));
    if (lane < 16) {
      red[w][0 * 16 + lane] = vmax0;
      red[w][1 * 16 + lane] = vmax1;
      red[w][2 * 16 + lane] = vmax2;
      red[w][3 * 16 + lane] = vmax3;
    }
    __syncthreads();
    if (t < 64) {
      float m4 = fmaxf(fmaxf(red[0][t], red[1][t]),
                       fmaxf(red[2][t], red[3][t]));
      ctxloc[t] = fmaxf(m4 + b2[t], 0.f);
    }
    __syncthreads();
    if (t < 64) {
      int l = t;
      float cl = ctxloc[l];
      float sc0 = cl * Wl2p[(32 + l) * 2 + 0];
      float sc1 = cl * Wl2p[(32 + l) * 2 + 1];
      float m0 = 0.f, m1 = 0.f, v0 = 0.f, v1 = 0.f;
      if (l < 32) {
        float hm = hloc[l];
        m0 = hm * Wl2p[l * 2 + 0]; m1 = hm * Wl2p[l * 2 + 1];
        float hv = hloc[32 + l];
        v0 = hv * Wl2p[l * 2 + 0]; v1 = hv * Wl2p[l * 2 + 1];
      }
      for (int off = 32; off >= 1; off >>= 1) {
        sc0 += __shfl_down(sc0, off);
        sc1 += __shfl_down(sc1, off);
        m0  += __shfl_down(m0,  off);
        m1  += __shfl_down(m1,  off);
        v0  += __shfl_down(v0,  off);
        v1  += __shfl_down(v1,  off);
      }
      if (l == 0) {
        float mu0 = m0 + sc0 + bl2p[0], mu1 = m1 + sc1 + bl2p[1];
        float lv0 = v0 + sc0 + bl2p[0], lv1 = v1 + sc1 + bl2p[1];
        float e0 = epsin[st * 1024 + b * 2 + 0];
        float e1 = epsin[st * 1024 + b * 2 + 1];
        float p0 = mu0 + e0 * expf(0.5f * lv0);
        float p1 = mu1 + e1 * expf(0.5f * lv1);
        out[st * 1024 + b * 2 + 0] = p0;
        out[st * 1024 + b * 2 + 1] = p1;
        out[12288 + st * 1024 + b * 2 + 0] = mu0;
        out[12288 + st * 1024 + b * 2 + 1] = mu1;
        out[24576 + st * 1024 + b * 2 + 0] = lv0;
        out[24576 + st * 1024 + b * 2 + 1] = lv1;
        float px = ws[OFF_CURABS + (st & 1) * 1024 + b * 2 + 0];
        float py = ws[OFF_CURABS + (st & 1) * 1024 + b * 2 + 1];
        float nx = px + p0, ny = py + p1;
        ws[OFF_CURABS + ((st & 1) ^ 1) * 1024 + b * 2 + 0] = nx;
        ws[OFF_CURABS + ((st & 1) ^ 1) * 1024 + b * 2 + 1] = ny;
        pxy[0] = nx; pxy[1] = ny;
        prevp[0] = p0; prevp[1] = p1;
      }
    }
    __syncthreads();
  }

  // ================= row phase: st = s =================
  if (s < TT) {
    {   // x = relu(Xcz + prev@W_in[0:2] + ctx@W_in[98:162] + b_in), split-K 2
      int k = t & 127, p = t >> 7;
      const __bf16* wctx = (const __bf16*)(ws + OFF_WCTXB);
      float a0 = 0.f, a1 = 0.f;
      if (p == 0)
        a0 = ws[OFF_XCZ + b * 128 + k] +
             prevp[0] * ws[OFF_WIN01 + k] + prevp[1] * ws[OFF_WIN01 + 128 + k];
      int d = p;
      for (; d + 2 < 64; d += 4) {
        a0 = fmaf(ctxloc[d],     (float)wctx[d * 128 + k],       a0);
        a1 = fmaf(ctxloc[d + 2], (float)wctx[(d + 2) * 128 + k], a1);
      }
      if (d < 64) a0 = fmaf(ctxloc[d], (float)wctx[d * 128 + k], a0);
      xpart[p][k] = a0 + a1;
    }
    __syncthreads();
    if (t < 128) xvec[t] = fmaxf(xpart[0][t] + xpart[1][t] + b_in[t], 0.f);
    __syncthreads();
    {   // gates: bf16 combined [x(128) | h(64)] x [256]
      int g = t;
      const __bf16* wgb = (const __bf16*)(ws + OFF_WGB);
      float s0 = 0.f, s1 = 0.f, s2 = 0.f, s3 = 0.f;
      for (int kk = 0; kk < 128; kk += 4) {
        s0 = fmaf(xvec[kk],     (float)wgb[kk * 256 + g],       s0);
        s1 = fmaf(xvec[kk + 1], (float)wgb[(kk + 1) * 256 + g], s1);
        s2 = fmaf(xvec[kk + 2], (float)wgb[(kk + 2) * 256 + g], s2);
        s3 = fmaf(xvec[kk + 3], (float)wgb[(kk + 3) * 256 + g], s3);
      }
      for (int kk = 0; kk < 64; kk += 4) {
        s0 = fmaf(hloc[kk],     (float)wgb[(128 + kk) * 256 + g],     s0);
        s1 = fmaf(hloc[kk + 1], (float)wgb[(129 + kk) * 256 + g],     s1);
        s2 = fmaf(hloc[kk + 2], (float)wgb[(130 + kk) * 256 + g],     s2);
        s3 = fmaf(hloc[kk + 3], (float)wgb[(131 + kk) * 256 + g],     s3);
      }
      gl[g] = b_ih[g] + b_hh[g] + ((s0 + s1) + (s2 + s3));
    }
    __syncthreads();
    if (t < 64) {   // LSTM update; persist h,cs for next dispatch
      float ig = gl[t], fg = gl[64 + t], gg = gl[128 + t], og = gl[192 + t];
      float is = 1.f / (1.f + expf(-ig));
      float fs = 1.f / (1.f + expf(-fg));
      float os = 1.f / (1.f + expf(-og));
      float cn = fs * csloc[t] + is * tanhf(gg);
      float hv = os * tanhf(cn);
      hloc[t] = hv;
      ws[OFF_CS + b * 64 + t] = cn;
      ws[OFF_H + b * 64 + t] = hv;
    }
    __syncthreads();
    if (t < 128) {  // Q(s) -> ws dbuf[s&1]; P(s) -> ws
      int which = t >> 6, m = t & 63;
      const __bf16* wb = (const __bf16*)(ws + OFF_W1B) + which * 4096 + m;
      float s0 = 0.f, s1 = 0.f, s2 = 0.f, s3 = 0.f;
      for (int k = 0; k < 64; k += 4) {
        s0 = fmaf(hloc[k],     (float)wb[k * 64],       s0);
        s1 = fmaf(hloc[k + 1], (float)wb[(k + 1) * 64], s1);
        s2 = fmaf(hloc[k + 2], (float)wb[(k + 2) * 64], s2);
        s3 = fmaf(hloc[k + 3], (float)wb[(k + 3) * 64], s3);
      }
      float sv = (s0 + s1) + (s2 + s3);
      float cx = pxy[0], cy = pxy[1];
      if (which == 0)
        ws[OFF_Q + (s & 1) * 32768 + b * 64 + m] =
            sv + basev[m] - cx * wcl[m] - cy * wcl[64 + m];
      else
        ws[OFF_P + b * 64 + m] = sv + cx * wcl[m] + cy * wcl[64 + m];
    }
  }
}

extern "C" void kernel_launch(void* const* d_in, const int* in_sizes, int n_in,
                              void* d_out, int out_size, void* d_ws, size_t ws_size,
                              hipStream_t stream) {
  const float* lastpos = (const float*)d_in[0];
  const float* cc      = (const float*)d_in[1];
  const float* zz      = (const float*)d_in[2];
  const float* obs     = (const float*)d_in[3];
  const int*   nei     = (const int*)d_in[4];
  const float* h0      = (const float*)d_in[6];
  const float* c0      = (const float*)d_in[7];
  const float* eps     = (const float*)d_in[8];
  const float* W_in    = (const float*)d_in[9];
  const float* b_in    = (const float*)d_in[10];
  const float* W_ih    = (const float*)d_in[11];
  const float* W_hh    = (const float*)d_in[12];
  const float* b_ih    = (const float*)d_in[13];
  const float* b_hh    = (const float*)d_in[14];
  const float* W_l2p   = (const float*)d_in[15];
  const float* b_l2p   = (const float*)d_in[16];
  const float* W_sp    = (const float*)d_in[17];
  const float* b_sp    = (const float*)d_in[18];
  const float* W1      = (const float*)d_in[19];
  const float* b1      = (const float*)d_in[20];
  const float* W2      = (const float*)d_in[21];
  const float* b2      = (const float*)d_in[22];
  float* out = (float*)d_out;
  float* ws  = (float*)d_ws;

  hipLaunchKernelGGL(init_k, dim3(640), dim3(256), 0, stream,
                     obs, cc, zz, W_in, W_ih, W_hh, W_sp, b_sp, W1, b1, ws);
  for (int s = 0; s <= TT; ++s) {
    hipLaunchKernelGGL(step_k, dim3(NP), dim3(256), 0, stream,
                       lastpos, nei, h0, c0, obs, eps,
                       b_in, b_ih, b_hh, W_l2p, b_l2p,
                       W2, b2, out, ws, s);
  }
}